// Round 7
// baseline (10074.200 us; speedup 1.0000x reference)
//
#include <hip/hip_runtime.h>
#include <cstdint>
#include <cstddef>

typedef unsigned short ushort_t;
typedef unsigned int uint_t;

#define NATOMS 8000
#define NEDGES 100000
#define NTRIP  500000
#define NGRAPH 64
#define HD     128
#define NRR    6
#define NSNR   42
#define NBB    8
#define NBLKS  6
#define MSZ    16384

using short8   = __attribute__((ext_vector_type(8))) short;
using ushort8v = __attribute__((ext_vector_type(8))) unsigned short;
using floatx4  = __attribute__((ext_vector_type(4))) float;

__device__ __forceinline__ float siluf(float x){ return x / (1.f + __expf(-x)); }
__device__ __forceinline__ ushort_t f2us(float f){
    uint_t u = __builtin_bit_cast(uint_t, f);
    u = (u + 0x7FFFu + ((u >> 16) & 1u)) >> 16;
    return (ushort_t)u;
}
__device__ __forceinline__ float us2f(ushort_t s){
    uint_t u = ((uint_t)s) << 16;
    return __builtin_bit_cast(float, u);
}

__global__ void zerof_k(float* __restrict__ p, int n){ int i=blockIdx.x*256+threadIdx.x; if(i<n) p[i]=0.f; }
__global__ void zeroi_k(int* __restrict__ p, int n){ int i=blockIdx.x*256+threadIdx.x; if(i<n) p[i]=0; }

// ---------------- weight prep ----------------
__global__ __launch_bounds__(256)
void transp128_k(const float* __restrict__ src, ushort_t* __restrict__ dst)
{
    __shared__ ushort_t L[128][130];
    int m = blockIdx.x;
    const float* S = src + (size_t)m * MSZ;
    ushort_t* D = dst + (size_t)m * MSZ;
    int tid = threadIdx.x;
    #pragma unroll
    for (int p = 0; p < 64; ++p) {
        int idx = p * 256 + tid;
        int k = idx >> 7, n = idx & 127;
        L[k][n] = f2us(S[idx]);
    }
    __syncthreads();
    #pragma unroll
    for (int p = 0; p < 64; ++p) {
        int idx = p * 256 + tid;
        int n = idx >> 7, k = idx & 127;
        D[idx] = L[k][n];
    }
}

// int_W [6][128][8][128] fp32 -> bf16 cast (same layout: wM[b][i][j*128+l])
__global__ void castWM_k(const float* __restrict__ src, ushort_t* __restrict__ dst, int n)
{
    int i = blockIdx.x * 256 + threadIdx.x;
    if (i < n) dst[i] = f2us(src[i]);
}

__global__ void pack_bc_k(const float* __restrict__ bef, const float* __restrict__ lin,
                          const float* __restrict__ aft, float* __restrict__ bc)
{
    int b = blockIdx.x;
    for (int i = threadIdx.x; i < 7 * HD; i += 256) {
        int s = i >> 7, h = i & 127;
        float v;
        if (s < 2)      v = bef[(size_t)(b * 2 + s) * HD + h];
        else if (s == 2) v = lin[(size_t)b * HD + h];
        else             v = aft[(size_t)(b * 4 + (s - 3)) * HD + h];
        bc[(size_t)b * 7 * HD + i] = v;
    }
}

// ---------------- CSR build ----------------
__global__ void hist_k(const int* __restrict__ idx, int n, int* __restrict__ cnt)
{
    int i = blockIdx.x * 256 + threadIdx.x;
    if (i < n) atomicAdd(&cnt[idx[i]], 1);
}
__global__ void blksum_k(const int* __restrict__ c, int n, int* __restrict__ bs)
{
    int i = blockIdx.x * 256 + threadIdx.x;
    int v = (i < n) ? c[i] : 0;
    #pragma unroll
    for (int off = 32; off; off >>= 1) v += __shfl_down(v, off);
    __shared__ int sh[4];
    if ((threadIdx.x & 63) == 0) sh[threadIdx.x >> 6] = v;
    __syncthreads();
    if (threadIdx.x == 0) bs[blockIdx.x] = sh[0] + sh[1] + sh[2] + sh[3];
}
__global__ void scanb_k(int* __restrict__ bs, int nb)
{
    __shared__ int sh[1024];
    int t = threadIdx.x;
    int v = (t < nb) ? bs[t] : 0;
    sh[t] = v; __syncthreads();
    for (int off = 1; off < 1024; off <<= 1) {
        int u = (t >= off) ? sh[t - off] : 0;
        __syncthreads();
        sh[t] += u;
        __syncthreads();
    }
    if (t < nb) bs[t] = sh[t] - v;
}
__global__ void scanfin_k(const int* __restrict__ c, int n, const int* __restrict__ bs,
                          int* __restrict__ offs)
{
    __shared__ int sh[256];
    int t = threadIdx.x;
    int i = blockIdx.x * 256 + t;
    int v = (i < n) ? c[i] : 0;
    sh[t] = v; __syncthreads();
    for (int off = 1; off < 256; off <<= 1) {
        int u = (t >= off) ? sh[t - off] : 0;
        __syncthreads();
        sh[t] += u;
        __syncthreads();
    }
    if (i < n)  offs[i] = bs[blockIdx.x] + sh[t] - v;
    if (i == n - 1) offs[n] = bs[blockIdx.x] + sh[t];
}
__global__ void fill_k(const int* __restrict__ idx, int n, const int* __restrict__ offs,
                       int* __restrict__ cur, int* __restrict__ sorted)
{
    int i = blockIdx.x * 256 + threadIdx.x;
    if (i >= n) return;
    int e = idx[i];
    int p = offs[e] + atomicAdd(&cur[e], 1);
    sorted[p] = i;
}

// ---------------------------------------------------------------------------
// Chain helpers
// ---------------------------------------------------------------------------
__device__ __forceinline__ void load_bh(const ushort_t* Bt, int kh, int tid, ushort8v r[4])
{
    #pragma unroll
    for (int p = 0; p < 4; ++p) {
        int c = p * 256 + tid;
        int n = c >> 3, c8 = c & 7;
        r[p] = *(const ushort8v*)(Bt + (size_t)n * 128 + kh * 64 + c8 * 8);
    }
}
__device__ __forceinline__ void load_bhs(const ushort_t* Bt, int ld, int kofs, int tid, ushort8v r[4])
{
    #pragma unroll
    for (int p = 0; p < 4; ++p) {
        int c = p * 256 + tid;
        int n = c >> 3, c8 = c & 7;
        r[p] = *(const ushort8v*)(Bt + (size_t)n * ld + kofs + c8 * 8);
    }
}
__device__ __forceinline__ void store_bh(ushort8v r[4], ushort_t (*Bl)[72], int tid)
{
    #pragma unroll
    for (int p = 0; p < 4; ++p) {
        int c = p * 256 + tid;
        *(ushort8v*)&Bl[c >> 3][(c & 7) * 8] = r[p];
    }
}
__device__ __forceinline__ void mfma_kh(ushort_t (*Al)[136], ushort_t (*Bl)[72],
                                        floatx4 acc[4][4], int kh,
                                        int wr, int wc, int lhi, int llo)
{
    #pragma unroll
    for (int ks = 0; ks < 2; ++ks) {
        int kk = ks * 32 + lhi * 8;
        short8 af[4], bf[4];
        #pragma unroll
        for (int tm = 0; tm < 4; ++tm)
            af[tm] = *(const short8*)&Al[wr * 64 + tm * 16 + llo][kh * 64 + kk];
        #pragma unroll
        for (int tn = 0; tn < 4; ++tn)
            bf[tn] = *(const short8*)&Bl[wc * 64 + tn * 16 + llo][kk];
        #pragma unroll
        for (int tm = 0; tm < 4; ++tm)
            #pragma unroll
            for (int tn = 0; tn < 4; ++tn)
                acc[tm][tn] = __builtin_amdgcn_mfma_f32_16x16x32_bf16(
                    af[tm], bf[tn], acc[tm][tn], 0, 0, 0);
    }
}
__device__ __forceinline__ void stage_a_bf16(const ushort_t* Xb, int M, int row0, int tid,
                                             ushort_t (*Al)[136])
{
    #pragma unroll
    for (int p = 0; p < 8; ++p) {
        int idx = p * 256 + tid;
        int r = idx >> 4, c8 = idx & 15;
        int grow = row0 + r; if (grow >= M) grow = M - 1;
        ushort8v v = *(const ushort8v*)(Xb + (size_t)grow * HD + c8 * 8);
        *(ushort8v*)&Al[r][c8 * 8] = v;
    }
}
__device__ __forceinline__ void stage_a_f32(const float* A, int M, int row0, int tid,
                                            ushort_t (*Al)[136])
{
    #pragma unroll
    for (int p = 0; p < 8; ++p) {
        int idx = p * 256 + tid;
        int r = idx >> 4, c8 = idx & 15;
        int grow = row0 + r; if (grow >= M) grow = M - 1;
        const float* s = A + (size_t)grow * HD + c8 * 8;
        float4 v0 = *(const float4*)s, v1 = *(const float4*)(s + 4);
        ushort8v pk;
        pk[0]=f2us(v0.x); pk[1]=f2us(v0.y); pk[2]=f2us(v0.z); pk[3]=f2us(v0.w);
        pk[4]=f2us(v1.x); pk[5]=f2us(v1.y); pk[6]=f2us(v1.z); pk[7]=f2us(v1.w);
        *(ushort8v*)&Al[r][c8 * 8] = pk;
    }
}
#define ZERO_ACC(acc) { _Pragma("unroll") for (int a_=0;a_<4;++a_) _Pragma("unroll") \
    for (int b_=0;b_<4;++b_) _Pragma("unroll") for (int q_=0;q_<4;++q_) acc[a_][b_][q_]=0.f; }

// ---------------------------------------------------------------------------
// Embedding chain
// ---------------------------------------------------------------------------
__global__ __launch_bounds__(256)
void emb_chain_k(const float* __restrict__ rbf, const float* __restrict__ W6g,
                 const float* __restrict__ b6g, const ushort_t* __restrict__ Wemb3,
                 const float* __restrict__ A0, const float* __restrict__ A1,
                 const float* __restrict__ emb_b, const int* __restrict__ z,
                 const int* __restrict__ ii, const int* __restrict__ jj,
                 float* __restrict__ X, ushort_t* __restrict__ Xb, int M)
{
    __shared__ ushort_t Al[128][136];
    __shared__ ushort_t Bl[128][72];
    __shared__ float W6[NRR * HD];
    __shared__ float b6s[HD];
    const int tid = threadIdx.x, row0 = blockIdx.x * 128;
    const int wave = tid >> 6, lane = tid & 63;
    const int wr = wave >> 1, wc_ = wave & 1, lhi = lane >> 4, llo = lane & 15;

    for (int i = tid; i < NRR * HD; i += 256) W6[i] = W6g[i];
    if (tid < HD) b6s[tid] = b6g[tid];
    ushort8v r0[4], r1[4];
    load_bh(Wemb3, 0, tid, r0); load_bh(Wemb3, 1, tid, r1);
    __syncthreads();

    {
        int e_l = tid >> 1, half = tid & 1;
        int grow = row0 + e_l; if (grow >= M) grow = M - 1;
        float r6[NRR];
        #pragma unroll
        for (int r = 0; r < NRR; ++r) r6[r] = rbf[(size_t)grow * NRR + r];
        #pragma unroll 8
        for (int hh = 0; hh < 64; ++hh) {
            int h = half * 64 + hh;
            float a = b6s[h];
            #pragma unroll
            for (int r = 0; r < NRR; ++r) a += r6[r] * W6[r * HD + h];
            Al[e_l][h] = f2us(siluf(a));
        }
    }
    __syncthreads();

    floatx4 acc[4][4]; ZERO_ACC(acc);
    store_bh(r0, Bl, tid); __syncthreads();
    mfma_kh(Al, Bl, acc, 0, wr, wc_, lhi, llo);
    __syncthreads();
    store_bh(r1, Bl, tid); __syncthreads();
    mfma_kh(Al, Bl, acc, 1, wr, wc_, lhi, llo);

    #pragma unroll
    for (int tm = 0; tm < 4; ++tm)
        #pragma unroll
        for (int q = 0; q < 4; ++q) {
            int grow = row0 + wr * 64 + tm * 16 + lhi * 4 + q;
            if (grow >= M) continue;
            int zi = z[ii[grow]], zj = z[jj[grow]];
            #pragma unroll
            for (int tn = 0; tn < 4; ++tn) {
                int coll = wc_ * 64 + tn * 16 + llo;
                float t = acc[tm][tn][q] + A0[zi * HD + coll] + A1[zj * HD + coll] + emb_b[coll];
                float v = siluf(t);
                size_t o = (size_t)grow * HD + coll;
                X[o] = v; Xb[o] = f2us(v);
            }
        }
}

// ---------------------------------------------------------------------------
// kjji: s0 = x_ji -> D (fp32); s1 = x_kj*rbfp -> Cb (bf16)
// ---------------------------------------------------------------------------
__global__ __launch_bounds__(256)
void kjji_k(const ushort_t* __restrict__ Xb,
            const ushort_t* __restrict__ Wji, const ushort_t* __restrict__ Wkj,
            const float* __restrict__ bji, const float* __restrict__ bkj,
            const float* __restrict__ rbf, const float* __restrict__ Wr6,
            float* __restrict__ D, ushort_t* __restrict__ Cb, int M)
{
    __shared__ ushort_t Al[128][136];
    __shared__ ushort_t Bl[128][72];
    __shared__ float Wr[NRR * HD];
    const int tid = threadIdx.x, row0 = blockIdx.x * 128;
    const int wave = tid >> 6, lane = tid & 63;
    const int wr = wave >> 1, wc_ = wave & 1, lhi = lane >> 4, llo = lane & 15;

    stage_a_bf16(Xb, M, row0, tid, Al);
    for (int i = tid; i < NRR * HD; i += 256) Wr[i] = Wr6[i];
    ushort8v r0[4], r1[4];
    load_bh(Wji, 0, tid, r0); load_bh(Wji, 1, tid, r1);

    for (int s = 0; s < 2; ++s) {
        floatx4 acc[4][4]; ZERO_ACC(acc);
        store_bh(r0, Bl, tid); __syncthreads();
        if (s < 1) load_bh(Wkj, 0, tid, r0);
        mfma_kh(Al, Bl, acc, 0, wr, wc_, lhi, llo);
        __syncthreads();
        store_bh(r1, Bl, tid); __syncthreads();
        if (s < 1) load_bh(Wkj, 1, tid, r1);
        mfma_kh(Al, Bl, acc, 1, wr, wc_, lhi, llo);
        __syncthreads();

        if (s == 0) {
            #pragma unroll
            for (int tm = 0; tm < 4; ++tm)
                #pragma unroll
                for (int tn = 0; tn < 4; ++tn) {
                    int coll = wc_ * 64 + tn * 16 + llo;
                    #pragma unroll
                    for (int q = 0; q < 4; ++q) {
                        int grow = row0 + wr * 64 + tm * 16 + lhi * 4 + q;
                        if (grow < M) D[(size_t)grow * HD + coll] = siluf(acc[tm][tn][q] + bji[coll]);
                    }
                }
        } else {
            #pragma unroll
            for (int tm = 0; tm < 4; ++tm)
                #pragma unroll
                for (int tn = 0; tn < 4; ++tn) {
                    int coll = wc_ * 64 + tn * 16 + llo;
                    #pragma unroll
                    for (int q = 0; q < 4; ++q) {
                        int grow = row0 + wr * 64 + tm * 16 + lhi * 4 + q;
                        if (grow >= M) continue;
                        float rp = 0.f;
                        #pragma unroll
                        for (int r = 0; r < NRR; ++r) rp += rbf[(size_t)grow * NRR + r] * Wr[r * HD + coll];
                        Cb[(size_t)grow * HD + coll] = f2us(siluf(acc[tm][tn][q] + bkj[coll]) * rp);
                    }
                }
        }
    }
}

// ---------------------------------------------------------------------------
// Triplet accumulate: G[e-c0, j*128+h] = sum_{t in T(e)} sp[t,j] * Cb[ekj[t], h]
// ---------------------------------------------------------------------------
__global__ __launch_bounds__(256)
void trip_accum_k(const ushort_t* __restrict__ sp, const ushort_t* __restrict__ Cb,
                  const int* __restrict__ toffs, const int* __restrict__ tsorted,
                  const int* __restrict__ idx_kj, ushort_t* __restrict__ G,
                  int c0, int c1)
{
    int e = c0 + blockIdx.x * 2 + (threadIdx.x >> 7);
    if (e >= c1) return;
    int h = threadIdx.x & 127;
    float acc[NBB];
    #pragma unroll
    for (int j = 0; j < NBB; ++j) acc[j] = 0.f;
    int k1 = toffs[e + 1];
    for (int k = toffs[e]; k < k1; ++k) {
        int t = tsorted[k];
        int ekj = idx_kj[t];
        float v = us2f(Cb[(size_t)ekj * HD + h]);
        ushort8v s8 = *(const ushort8v*)(sp + (size_t)t * NBB);
        #pragma unroll
        for (int j = 0; j < NBB; ++j) acc[j] += us2f(s8[j]) * v;
    }
    ushort_t* g = G + (size_t)(e - c0) * 1024 + h;
    #pragma unroll
    for (int j = 0; j < NBB; ++j) g[j * HD] = f2us(acc[j]);
}

// ---------------------------------------------------------------------------
// K=1024 GEMM: D[c0+row, :] += G[row, 0..1023] @ Wm   (Wm[i][k], ld 1024)
// ---------------------------------------------------------------------------
__global__ __launch_bounds__(256)
void mgemmK_k(const ushort_t* __restrict__ G, int Mrows,
              const ushort_t* __restrict__ Wm, float* __restrict__ D, int c0)
{
    __shared__ ushort_t Al[128][136];
    __shared__ ushort_t Bl[128][72];
    const int tid = threadIdx.x, row0 = blockIdx.x * 128;
    const int wave = tid >> 6, lane = tid & 63;
    const int wr = wave >> 1, wc_ = wave & 1, lhi = lane >> 4, llo = lane & 15;

    floatx4 acc[4][4]; ZERO_ACC(acc);
    ushort8v r0[4], r1[4];
    load_bhs(Wm, 1024, 0, tid, r0);
    load_bhs(Wm, 1024, 64, tid, r1);

    for (int kt = 0; kt < 8; ++kt) {
        __syncthreads();   // prior mfma done -> safe to rewrite Al/Bl
        // stage A tile (128 rows x 128 k) from G
        #pragma unroll
        for (int p = 0; p < 8; ++p) {
            int idx = p * 256 + tid;
            int r = idx >> 4, c8 = idx & 15;
            int grow = row0 + r; if (grow >= Mrows) grow = Mrows - 1;
            ushort8v v = *(const ushort8v*)(G + (size_t)grow * 1024 + kt * 128 + c8 * 8);
            *(ushort8v*)&Al[r][c8 * 8] = v;
        }
        store_bh(r0, Bl, tid);
        __syncthreads();
        if (kt < 7) load_bhs(Wm, 1024, (kt + 1) * 128, tid, r0);
        mfma_kh(Al, Bl, acc, 0, wr, wc_, lhi, llo);
        __syncthreads();
        store_bh(r1, Bl, tid);
        __syncthreads();
        if (kt < 7) load_bhs(Wm, 1024, (kt + 1) * 128 + 64, tid, r1);
        mfma_kh(Al, Bl, acc, 1, wr, wc_, lhi, llo);
    }

    #pragma unroll
    for (int tm = 0; tm < 4; ++tm)
        #pragma unroll
        for (int tn = 0; tn < 4; ++tn) {
            int coll = wc_ * 64 + tn * 16 + llo;
            #pragma unroll
            for (int q = 0; q < 4; ++q) {
                int grow = row0 + wr * 64 + tm * 16 + lhi * 4 + q;
                if (grow >= Mrows) continue;
                size_t o = (size_t)(c0 + grow) * HD + coll;
                D[o] += acc[tm][tn][q];
            }
        }
}

// ---------------------------------------------------------------------------
// Mega chain: bef0,bef1(+Din),lin(+X),aft0..3(+X) ; writes X fp32 + Xb bf16
// ---------------------------------------------------------------------------
__global__ __launch_bounds__(256)
void mega_k(const float* __restrict__ Din, float* __restrict__ X, ushort_t* __restrict__ Xb,
            const ushort_t* __restrict__ Wc, const float* __restrict__ Bc, int M)
{
    __shared__ ushort_t Al[128][136];
    __shared__ ushort_t Bl[128][72];
    const int tid = threadIdx.x, row0 = blockIdx.x * 128;
    const int wave = tid >> 6, lane = tid & 63;
    const int wr = wave >> 1, wc_ = wave & 1, lhi = lane >> 4, llo = lane & 15;

    stage_a_f32(Din, M, row0, tid, Al);
    ushort8v r0[4], r1[4];
    load_bh(Wc, 0, tid, r0); load_bh(Wc, 1, tid, r1);

    for (int s = 0; s < 7; ++s) {
        const ushort_t* nxt = Wc + (size_t)(s + 1) * MSZ;
        floatx4 acc[4][4]; ZERO_ACC(acc);
        store_bh(r0, Bl, tid); __syncthreads();
        if (s < 6) load_bh(nxt, 0, tid, r0);
        mfma_kh(Al, Bl, acc, 0, wr, wc_, lhi, llo);
        __syncthreads();
        store_bh(r1, Bl, tid); __syncthreads();
        if (s < 6) load_bh(nxt, 1, tid, r1);
        mfma_kh(Al, Bl, acc, 1, wr, wc_, lhi, llo);
        __syncthreads();

        #pragma unroll
        for (int tm = 0; tm < 4; ++tm)
            #pragma unroll
            for (int tn = 0; tn < 4; ++tn) {
                int coll = wc_ * 64 + tn * 16 + llo;
                #pragma unroll
                for (int q = 0; q < 4; ++q) {
                    int rowl = wr * 64 + tm * 16 + lhi * 4 + q;
                    int grow = row0 + rowl;
                    bool ok = grow < M;
                    size_t gofs = (size_t)grow * HD + coll;
                    float t = siluf(acc[tm][tn][q] + Bc[s * HD + coll]);
                    float h;
                    if (s == 0 || s == 3 || s == 5) h = t;
                    else if (s == 1) h = t + (ok ? Din[gofs] : 0.f);
                    else {
                        float base = ok ? X[gofs] : 0.f;
                        h = t + base;
                        if (ok) { X[gofs] = h; if (s == 6) Xb[gofs] = f2us(h); }
                    }
                    if (s < 6) Al[rowl][coll] = f2us(h);
                }
            }
    }
}

// ---------------------------------------------------------------------------
// Fused out-block: CSR atom gather + 3 silu-lins + out_w dot -> P
// ---------------------------------------------------------------------------
__global__ __launch_bounds__(256)
void atomout_k(const ushort_t* __restrict__ Xb, const float* __restrict__ rbf,
               const float* __restrict__ Wr6, const int* __restrict__ eoffs,
               const int* __restrict__ esorted, const ushort_t* __restrict__ Wl,
               const float* __restrict__ bl, const float* __restrict__ wout,
               float* __restrict__ P, int M)
{
    __shared__ ushort_t Al[128][136];
    __shared__ ushort_t Bl[128][72];
    __shared__ float Wr[NRR * HD];
    const int tid = threadIdx.x, row0 = blockIdx.x * 128;
    const int wave = tid >> 6, lane = tid & 63;
    const int wr = wave >> 1, wc_ = wave & 1, lhi = lane >> 4, llo = lane & 15;

    for (int i = tid; i < NRR * HD; i += 256) Wr[i] = Wr6[i];
    ushort8v r0[4], r1[4];
    load_bh(Wl, 0, tid, r0); load_bh(Wl, 1, tid, r1);
    __syncthreads();

    {
        int half = tid >> 7, h = tid & 127;
        for (int pi = 0; pi < 64; ++pi) {
            int a_l = pi * 2 + half;
            int a = row0 + a_l;
            float acc = 0.f;
            if (a < M) {
                int k1 = eoffs[a + 1];
                for (int k = eoffs[a]; k < k1; ++k) {
                    int e = esorted[k];
                    float rp = 0.f;
                    #pragma unroll
                    for (int r = 0; r < NRR; ++r) rp += rbf[(size_t)e * NRR + r] * Wr[r * HD + h];
                    acc += rp * us2f(Xb[(size_t)e * HD + h]);
                }
            }
            Al[a_l][h] = f2us(acc);
        }
    }
    float wv[4];
    #pragma unroll
    for (int tn = 0; tn < 4; ++tn) wv[tn] = wout[wc_ * 64 + tn * 16 + llo];
    __syncthreads();

    for (int s = 0; s < 3; ++s) {
        const ushort_t* nxt = Wl + (size_t)(s + 1) * MSZ;
        floatx4 acc[4][4]; ZERO_ACC(acc);
        store_bh(r0, Bl, tid); __syncthreads();
        if (s < 2) load_bh(nxt, 0, tid, r0);
        mfma_kh(Al, Bl, acc, 0, wr, wc_, lhi, llo);
        __syncthreads();
        store_bh(r1, Bl, tid); __syncthreads();
        if (s < 2) load_bh(nxt, 1, tid, r1);
        mfma_kh(Al, Bl, acc, 1, wr, wc_, lhi, llo);
        __syncthreads();

        if (s < 2) {
            #pragma unroll
            for (int tm = 0; tm < 4; ++tm)
                #pragma unroll
                for (int tn = 0; tn < 4; ++tn) {
                    int coll = wc_ * 64 + tn * 16 + llo;
                    #pragma unroll
                    for (int q = 0; q < 4; ++q) {
                        int rowl = wr * 64 + tm * 16 + lhi * 4 + q;
                        Al[rowl][coll] = f2us(siluf(acc[tm][tn][q] + bl[s * HD + coll]));
                    }
                }
        } else {
            #pragma unroll
            for (int tm = 0; tm < 4; ++tm)
                #pragma unroll
                for (int q = 0; q < 4; ++q) {
                    float v = 0.f;
                    #pragma unroll
                    for (int tn = 0; tn < 4; ++tn) {
                        int coll = wc_ * 64 + tn * 16 + llo;
                        v += siluf(acc[tm][tn][q] + bl[2 * HD + coll]) * wv[tn];
                    }
                    v += __shfl_xor(v, 1); v += __shfl_xor(v, 2);
                    v += __shfl_xor(v, 4); v += __shfl_xor(v, 8);
                    int grow = row0 + wr * 64 + tm * 16 + lhi * 4 + q;
                    if (llo == 0 && grow < M) atomicAdd(&P[grow], v);
                }
        }
    }
}

// ---------------- small kernels ----------------
__global__ void emb_lin_k(const float* __restrict__ emb_table, const float* __restrict__ emb_w,
                          float* __restrict__ A0, float* __restrict__ A1)
{
    __shared__ float er[HD];
    int a = blockIdx.x, h = threadIdx.x;
    er[h] = emb_table[a * HD + h];
    __syncthreads();
    float acc0 = 0.f, acc1 = 0.f;
    #pragma unroll 8
    for (int l = 0; l < HD; ++l) {
        float e = er[l];
        acc0 += e * emb_w[l * HD + h];
        acc1 += e * emb_w[(HD + l) * HD + h];
    }
    A0[a * HD + h] = acc0;
    A1[a * HD + h] = acc1;
}

__global__ void sbf_proj_k(const float* __restrict__ sbf, const float* __restrict__ W,
                           ushort_t* __restrict__ sp)
{
    __shared__ float Ws[NSNR * NBB];
    for (int s = threadIdx.x; s < NSNR * NBB; s += 256) Ws[s] = W[s];
    __syncthreads();
    int t = blockIdx.x * 256 + threadIdx.x;
    if (t >= NTRIP) return;
    float acc[NBB];
    #pragma unroll
    for (int n = 0; n < NBB; ++n) acc[n] = 0.f;
    #pragma unroll
    for (int r = 0; r < NSNR; ++r) {
        float v = sbf[(size_t)t * NSNR + r];
        #pragma unroll
        for (int n = 0; n < NBB; ++n) acc[n] += v * Ws[r * NBB + n];
    }
    #pragma unroll
    for (int n = 0; n < NBB; ++n) sp[(size_t)t * NBB + n] = f2us(acc[n]);
}

__global__ void graph_sum_k(const float* __restrict__ P, const int* __restrict__ batch,
                            float* __restrict__ outg)
{
    int a = blockIdx.x * 256 + threadIdx.x;
    if (a >= NATOMS) return;
    atomicAdd(&outg[batch[a]], P[a]);
}

// ---------------------------------------------------------------------------
extern "C" void kernel_launch(void* const* d_in, const int* in_sizes, int n_in,
                              void* d_out, int out_size, void* d_ws, size_t ws_size,
                              hipStream_t stream)
{
    const int*   z         = (const int*)  d_in[0];
    const float* rbf       = (const float*)d_in[1];
    const float* sbf       = (const float*)d_in[2];
    const int*   ii        = (const int*)  d_in[3];
    const int*   jj        = (const int*)  d_in[4];
    const int*   idx_kj    = (const int*)  d_in[5];
    const int*   idx_ji    = (const int*)  d_in[6];
    const int*   batch     = (const int*)  d_in[7];
    const float* emb_table = (const float*)d_in[8];
    const float* emb_rbf_w = (const float*)d_in[9];
    const float* emb_rbf_b = (const float*)d_in[10];
    const float* emb_w     = (const float*)d_in[11];
    const float* emb_b     = (const float*)d_in[12];
    const float* int_rbf_w = (const float*)d_in[13];
    const float* int_sbf_w = (const float*)d_in[14];
    const float* int_kj_w  = (const float*)d_in[15];
    const float* int_kj_b  = (const float*)d_in[16];
    const float* int_ji_w  = (const float*)d_in[17];
    const float* int_ji_b  = (const float*)d_in[18];
    const float* int_W     = (const float*)d_in[19];
    const float* int_bef_w = (const float*)d_in[20];
    const float* int_bef_b = (const float*)d_in[21];
    const float* int_lin_w = (const float*)d_in[22];
    const float* int_lin_b = (const float*)d_in[23];
    const float* int_aft_w = (const float*)d_in[24];
    const float* int_aft_b = (const float*)d_in[25];
    const float* out_rbf_w = (const float*)d_in[26];
    const float* out_lins_w= (const float*)d_in[27];
    const float* out_lins_b= (const float*)d_in[28];
    const float* out_w     = (const float*)d_in[29];
    float* d_outf          = (float*)d_out;

    const size_t EH = (size_t)NEDGES * HD;
    const int OFF_EMB = 0, OFF_KJ = 1, OFF_JI = 7, OFF_CHAIN = 13, OFF_OUTL = 55;

    char* base = (char*)d_ws;
    auto take = [&](size_t bytes) { char* p = base; base += (bytes + 255) & ~(size_t)255; return p; };
    float* bufA    = (float*)take(EH * 4);                     // X fp32
    float* bufD    = (float*)take(EH * 4);                     // x_ji + m
    ushort_t* Xb   = (ushort_t*)take(EH * 2);                  // X bf16 shadow
    ushort_t* Cb   = (ushort_t*)take(EH * 2);                  // x_kj bf16
    ushort_t* sbfp = (ushort_t*)take((size_t)NTRIP * NBB * 2); // sp bf16
    float* P_atom  = (float*)take((size_t)NATOMS * 4);
    float* A0      = (float*)take(95 * HD * 4);
    float* A1      = (float*)take(95 * HD * 4);
    float* bc      = (float*)take((size_t)NBLKS * 7 * HD * 4);
    int*   counts  = (int*)  take((size_t)(NEDGES + 1) * 4);
    int*   bsum    = (int*)  take(1024 * 4);
    int*   toffs   = (int*)  take((size_t)(NEDGES + 1) * 4);
    int*   eoffs   = (int*)  take((size_t)(NATOMS + 1) * 4);
    int*   tsorted = (int*)  take((size_t)NTRIP * 4);
    int*   esorted = (int*)  take((size_t)NEDGES * 4);
    ushort_t* w128 = (ushort_t*)take((size_t)76 * MSZ * 2);
    ushort_t* wM   = (ushort_t*)take((size_t)NBLKS * HD * 1024 * 2);
    size_t fixed   = (size_t)(base - (char*)d_ws);
    ushort_t* G    = (ushort_t*)base;

    // adaptive G chunking: smallest #chunks whose slice fits remaining ws
    int nch = 8;
    for (int c = 1; c <= 8; ++c) {
        size_t gb = (size_t)((NEDGES + c - 1) / c) * 1024 * 2;
        if (fixed + gb <= ws_size) { nch = c; break; }
    }
    const int CH = (NEDGES + nch - 1) / nch;

    auto zero = [&](float* p, size_t n) {
        zerof_k<<<((int)n + 255) / 256, 256, 0, stream>>>(p, (int)n);
    };

    // ---------------- weight prep ----------------
    transp128_k<<< 1, 256, 0, stream>>>(emb_w + 2 * MSZ, w128 + (size_t)OFF_EMB * MSZ);
    transp128_k<<< 6, 256, 0, stream>>>(int_kj_w,   w128 + (size_t)OFF_KJ  * MSZ);
    transp128_k<<< 6, 256, 0, stream>>>(int_ji_w,   w128 + (size_t)OFF_JI  * MSZ);
    for (int b = 0; b < NBLKS; ++b) {
        transp128_k<<<2, 256, 0, stream>>>(int_bef_w + (size_t)b * 2 * MSZ,
                                           w128 + (size_t)(OFF_CHAIN + b * 7) * MSZ);
        transp128_k<<<1, 256, 0, stream>>>(int_lin_w + (size_t)b * MSZ,
                                           w128 + (size_t)(OFF_CHAIN + b * 7 + 2) * MSZ);
        transp128_k<<<4, 256, 0, stream>>>(int_aft_w + (size_t)b * 4 * MSZ,
                                           w128 + (size_t)(OFF_CHAIN + b * 7 + 3) * MSZ);
    }
    transp128_k<<<21, 256, 0, stream>>>(out_lins_w, w128 + (size_t)OFF_OUTL * MSZ);
    castWM_k<<<(NBLKS * HD * 1024 + 255) / 256, 256, 0, stream>>>(int_W, wM, NBLKS * HD * 1024);
    pack_bc_k<<<NBLKS, 256, 0, stream>>>(int_bef_b, int_lin_b, int_aft_b, bc);

    // ---------------- CSR builds ----------------
    {
        zeroi_k<<<(NEDGES + 255) / 256, 256, 0, stream>>>(counts, NEDGES);
        hist_k<<<(NTRIP + 255) / 256, 256, 0, stream>>>(idx_ji, NTRIP, counts);
        int nb = (NEDGES + 255) / 256;
        blksum_k<<<nb, 256, 0, stream>>>(counts, NEDGES, bsum);
        scanb_k<<<1, 1024, 0, stream>>>(bsum, nb);
        scanfin_k<<<nb, 256, 0, stream>>>(counts, NEDGES, bsum, toffs);
        zeroi_k<<<(NEDGES + 255) / 256, 256, 0, stream>>>(counts, NEDGES);
        fill_k<<<(NTRIP + 255) / 256, 256, 0, stream>>>(idx_ji, NTRIP, toffs, counts, tsorted);
    }
    {
        zeroi_k<<<(NATOMS + 255) / 256, 256, 0, stream>>>(counts, NATOMS);
        hist_k<<<(NEDGES + 255) / 256, 256, 0, stream>>>(ii, NEDGES, counts);
        int nb = (NATOMS + 255) / 256;
        blksum_k<<<nb, 256, 0, stream>>>(counts, NATOMS, bsum);
        scanb_k<<<1, 1024, 0, stream>>>(bsum, nb);
        scanfin_k<<<nb, 256, 0, stream>>>(counts, NATOMS, bsum, eoffs);
        zeroi_k<<<(NATOMS + 255) / 256, 256, 0, stream>>>(counts, NATOMS);
        fill_k<<<(NEDGES + 255) / 256, 256, 0, stream>>>(ii, NEDGES, eoffs, counts, esorted);
    }

    const int EGRID = (NEDGES + 127) / 128;
    const int AGRID = (NATOMS + 127) / 128;
    auto out_block = [&](int k) {
        atomout_k<<<AGRID, 256, 0, stream>>>(
            Xb, rbf, out_rbf_w + (size_t)k * NRR * HD, eoffs, esorted,
            w128 + (size_t)(OFF_OUTL + 3 * k) * MSZ,
            out_lins_b + (size_t)k * 3 * HD, out_w + (size_t)k * HD, P_atom, NATOMS);
    };

    // ---------------- Embedding ----------------
    emb_lin_k<<<95, HD, 0, stream>>>(emb_table, emb_w, A0, A1);
    emb_chain_k<<<EGRID, 256, 0, stream>>>(
        rbf, emb_rbf_w, emb_rbf_b, w128 + (size_t)OFF_EMB * MSZ,
        A0, A1, emb_b, z, ii, jj, bufA, Xb, NEDGES);

    zero(P_atom, NATOMS);
    out_block(0);

    // ---------------- Interaction blocks ----------------
    for (int b = 0; b < NBLKS; ++b) {
        sbf_proj_k<<<(NTRIP + 255) / 256, 256, 0, stream>>>(
            sbf, int_sbf_w + (size_t)b * NSNR * NBB, sbfp);

        kjji_k<<<EGRID, 256, 0, stream>>>(
            Xb, w128 + (size_t)(OFF_JI + b) * MSZ, w128 + (size_t)(OFF_KJ + b) * MSZ,
            int_ji_b + (size_t)b * HD, int_kj_b + (size_t)b * HD,
            rbf, int_rbf_w + (size_t)b * NRR * HD,
            bufD, Cb, NEDGES);

        for (int c = 0; c < nch; ++c) {
            int c0 = c * CH;
            int c1 = (c0 + CH < NEDGES) ? c0 + CH : NEDGES;
            if (c0 >= c1) break;
            int ne = c1 - c0;
            trip_accum_k<<<(ne + 1) / 2, 256, 0, stream>>>(
                sbfp, Cb, toffs, tsorted, idx_kj, G, c0, c1);
            mgemmK_k<<<(ne + 127) / 128, 256, 0, stream>>>(
                G, ne, wM + (size_t)b * HD * 1024, bufD, c0);
        }

        mega_k<<<EGRID, 256, 0, stream>>>(
            bufD, bufA, Xb, w128 + (size_t)(OFF_CHAIN + b * 7) * MSZ,
            bc + (size_t)b * 7 * HD, NEDGES);

        out_block(b + 1);
    }

    // ---------------- Final graph reduction ----------------
    zero(d_outf, NGRAPH);
    graph_sum_k<<<(NATOMS + 255) / 256, 256, 0, stream>>>(P_atom, batch, d_outf);
}

// Round 8
// 6063.500 us; speedup vs baseline: 1.6614x; 1.6614x over previous
//
#include <hip/hip_runtime.h>
#include <cstdint>
#include <cstddef>

typedef unsigned short ushort_t;
typedef unsigned int uint_t;

#define NATOMS 8000
#define NEDGES 100000
#define NTRIP  500000
#define NGRAPH 64
#define HD     128
#define NRR    6
#define NSNR   42
#define NBB    8
#define NBLKS  6
#define MSZ    16384

using short8   = __attribute__((ext_vector_type(8))) short;
using ushort8v = __attribute__((ext_vector_type(8))) unsigned short;
using floatx4  = __attribute__((ext_vector_type(4))) float;

__device__ __forceinline__ float siluf(float x){ return x / (1.f + __expf(-x)); }
__device__ __forceinline__ ushort_t f2us(float f){
    uint_t u = __builtin_bit_cast(uint_t, f);
    u = (u + 0x7FFFu + ((u >> 16) & 1u)) >> 16;
    return (ushort_t)u;
}
__device__ __forceinline__ float us2f(ushort_t s){
    uint_t u = ((uint_t)s) << 16;
    return __builtin_bit_cast(float, u);
}
// wave-private LDS RAW fence: wait own ds_writes, no block barrier, no vmcnt drain
__device__ __forceinline__ void wave_lds_fence(){
    asm volatile("s_waitcnt lgkmcnt(0)" ::: "memory");
}

__global__ void zerof_k(float* __restrict__ p, int n){ int i=blockIdx.x*256+threadIdx.x; if(i<n) p[i]=0.f; }
__global__ void zeroi_k(int* __restrict__ p, int n){ int i=blockIdx.x*256+threadIdx.x; if(i<n) p[i]=0; }

// ---------------- weight prep ----------------
__global__ __launch_bounds__(256)
void transp128_k(const float* __restrict__ src, ushort_t* __restrict__ dst)
{
    __shared__ ushort_t L[128][130];
    int m = blockIdx.x;
    const float* S = src + (size_t)m * MSZ;
    ushort_t* D = dst + (size_t)m * MSZ;
    int tid = threadIdx.x;
    #pragma unroll
    for (int p = 0; p < 64; ++p) {
        int idx = p * 256 + tid;
        int k = idx >> 7, n = idx & 127;
        L[k][n] = f2us(S[idx]);
    }
    __syncthreads();
    #pragma unroll
    for (int p = 0; p < 64; ++p) {
        int idx = p * 256 + tid;
        int n = idx >> 7, k = idx & 127;
        D[idx] = L[k][n];
    }
}

__global__ void castWM_k(const float* __restrict__ src, ushort_t* __restrict__ dst, int n)
{
    int i = blockIdx.x * 256 + threadIdx.x;
    if (i < n) dst[i] = f2us(src[i]);
}

__global__ void pack_bc_k(const float* __restrict__ bef, const float* __restrict__ lin,
                          const float* __restrict__ aft, float* __restrict__ bc)
{
    int b = blockIdx.x;
    for (int i = threadIdx.x; i < 7 * HD; i += 256) {
        int s = i >> 7, h = i & 127;
        float v;
        if (s < 2)      v = bef[(size_t)(b * 2 + s) * HD + h];
        else if (s == 2) v = lin[(size_t)b * HD + h];
        else             v = aft[(size_t)(b * 4 + (s - 3)) * HD + h];
        bc[(size_t)b * 7 * HD + i] = v;
    }
}

// ---------------- CSR build ----------------
__global__ void hist_k(const int* __restrict__ idx, int n, int* __restrict__ cnt)
{
    int i = blockIdx.x * 256 + threadIdx.x;
    if (i < n) atomicAdd(&cnt[idx[i]], 1);
}
__global__ void blksum_k(const int* __restrict__ c, int n, int* __restrict__ bs)
{
    int i = blockIdx.x * 256 + threadIdx.x;
    int v = (i < n) ? c[i] : 0;
    #pragma unroll
    for (int off = 32; off; off >>= 1) v += __shfl_down(v, off);
    __shared__ int sh[4];
    if ((threadIdx.x & 63) == 0) sh[threadIdx.x >> 6] = v;
    __syncthreads();
    if (threadIdx.x == 0) bs[blockIdx.x] = sh[0] + sh[1] + sh[2] + sh[3];
}
__global__ void scanb_k(int* __restrict__ bs, int nb)
{
    __shared__ int sh[1024];
    int t = threadIdx.x;
    int v = (t < nb) ? bs[t] : 0;
    sh[t] = v; __syncthreads();
    for (int off = 1; off < 1024; off <<= 1) {
        int u = (t >= off) ? sh[t - off] : 0;
        __syncthreads();
        sh[t] += u;
        __syncthreads();
    }
    if (t < nb) bs[t] = sh[t] - v;
}
__global__ void scanfin_k(const int* __restrict__ c, int n, const int* __restrict__ bs,
                          int* __restrict__ offs)
{
    __shared__ int sh[256];
    int t = threadIdx.x;
    int i = blockIdx.x * 256 + t;
    int v = (i < n) ? c[i] : 0;
    sh[t] = v; __syncthreads();
    for (int off = 1; off < 256; off <<= 1) {
        int u = (t >= off) ? sh[t - off] : 0;
        __syncthreads();
        sh[t] += u;
        __syncthreads();
    }
    if (i < n)  offs[i] = bs[blockIdx.x] + sh[t] - v;
    if (i == n - 1) offs[n] = bs[blockIdx.x] + sh[t];
}
__global__ void fill_k(const int* __restrict__ idx, int n, const int* __restrict__ offs,
                       int* __restrict__ cur, int* __restrict__ sorted)
{
    int i = blockIdx.x * 256 + threadIdx.x;
    if (i >= n) return;
    int e = idx[i];
    int p = offs[e] + atomicAdd(&cur[e], 1);
    sorted[p] = i;
}

// ---------------------------------------------------------------------------
// Legacy block helpers (used only by emb_chain_k, single dispatch)
// ---------------------------------------------------------------------------
__device__ __forceinline__ void load_bh(const ushort_t* Bt, int kh, int tid, ushort8v r[4])
{
    #pragma unroll
    for (int p = 0; p < 4; ++p) {
        int c = p * 256 + tid;
        int n = c >> 3, c8 = c & 7;
        r[p] = *(const ushort8v*)(Bt + (size_t)n * 128 + kh * 64 + c8 * 8);
    }
}
__device__ __forceinline__ void store_bh(ushort8v r[4], ushort_t (*Bl)[72], int tid)
{
    #pragma unroll
    for (int p = 0; p < 4; ++p) {
        int c = p * 256 + tid;
        *(ushort8v*)&Bl[c >> 3][(c & 7) * 8] = r[p];
    }
}
__device__ __forceinline__ void mfma_kh(ushort_t (*Al)[136], ushort_t (*Bl)[72],
                                        floatx4 acc[4][4], int kh,
                                        int wr, int wc, int lhi, int llo)
{
    #pragma unroll
    for (int ks = 0; ks < 2; ++ks) {
        int kk = ks * 32 + lhi * 8;
        short8 af[4], bf[4];
        #pragma unroll
        for (int tm = 0; tm < 4; ++tm)
            af[tm] = *(const short8*)&Al[wr * 64 + tm * 16 + llo][kh * 64 + kk];
        #pragma unroll
        for (int tn = 0; tn < 4; ++tn)
            bf[tn] = *(const short8*)&Bl[wc * 64 + tn * 16 + llo][kk];
        #pragma unroll
        for (int tm = 0; tm < 4; ++tm)
            #pragma unroll
            for (int tn = 0; tn < 4; ++tn)
                acc[tm][tn] = __builtin_amdgcn_mfma_f32_16x16x32_bf16(
                    af[tm], bf[tn], acc[tm][tn], 0, 0, 0);
    }
}
#define ZERO_ACC(acc) { _Pragma("unroll") for (int a_=0;a_<4;++a_) _Pragma("unroll") \
    for (int b_=0;b_<4;++b_) _Pragma("unroll") for (int q_=0;q_<4;++q_) acc[a_][b_][q_]=0.f; }

// ---------------------------------------------------------------------------
// Embedding chain (single dispatch; block-tiled, validated in r7)
// ---------------------------------------------------------------------------
__global__ __launch_bounds__(256)
void emb_chain_k(const float* __restrict__ rbf, const float* __restrict__ W6g,
                 const float* __restrict__ b6g, const ushort_t* __restrict__ Wemb3,
                 const float* __restrict__ A0, const float* __restrict__ A1,
                 const float* __restrict__ emb_b, const int* __restrict__ z,
                 const int* __restrict__ ii, const int* __restrict__ jj,
                 float* __restrict__ X, ushort_t* __restrict__ Xb, int M)
{
    __shared__ ushort_t Al[128][136];
    __shared__ ushort_t Bl[128][72];
    __shared__ float W6[NRR * HD];
    __shared__ float b6s[HD];
    const int tid = threadIdx.x, row0 = blockIdx.x * 128;
    const int wave = tid >> 6, lane = tid & 63;
    const int wr = wave >> 1, wc_ = wave & 1, lhi = lane >> 4, llo = lane & 15;

    for (int i = tid; i < NRR * HD; i += 256) W6[i] = W6g[i];
    if (tid < HD) b6s[tid] = b6g[tid];
    ushort8v r0[4], r1[4];
    load_bh(Wemb3, 0, tid, r0); load_bh(Wemb3, 1, tid, r1);
    __syncthreads();

    {
        int e_l = tid >> 1, half = tid & 1;
        int grow = row0 + e_l; if (grow >= M) grow = M - 1;
        float r6[NRR];
        #pragma unroll
        for (int r = 0; r < NRR; ++r) r6[r] = rbf[(size_t)grow * NRR + r];
        #pragma unroll 8
        for (int hh = 0; hh < 64; ++hh) {
            int h = half * 64 + hh;
            float a = b6s[h];
            #pragma unroll
            for (int r = 0; r < NRR; ++r) a += r6[r] * W6[r * HD + h];
            Al[e_l][h] = f2us(siluf(a));
        }
    }
    __syncthreads();

    floatx4 acc[4][4]; ZERO_ACC(acc);
    store_bh(r0, Bl, tid); __syncthreads();
    mfma_kh(Al, Bl, acc, 0, wr, wc_, lhi, llo);
    __syncthreads();
    store_bh(r1, Bl, tid); __syncthreads();
    mfma_kh(Al, Bl, acc, 1, wr, wc_, lhi, llo);

    #pragma unroll
    for (int tm = 0; tm < 4; ++tm)
        #pragma unroll
        for (int q = 0; q < 4; ++q) {
            int grow = row0 + wr * 64 + tm * 16 + lhi * 4 + q;
            if (grow >= M) continue;
            int zi = z[ii[grow]], zj = z[jj[grow]];
            #pragma unroll
            for (int tn = 0; tn < 4; ++tn) {
                int coll = wc_ * 64 + tn * 16 + llo;
                float t = acc[tm][tn][q] + A0[zi * HD + coll] + A1[zj * HD + coll] + emb_b[coll];
                float v = siluf(t);
                size_t o = (size_t)grow * HD + coll;
                X[o] = v; Xb[o] = f2us(v);
            }
        }
}

// ---------------------------------------------------------------------------
// Wave-autonomous kjji: per wave 16 rows. s0: x_ji -> D (fp32);
// s1: silu(x@Wkj+b)*rbfp -> Cb (bf16). A-frags direct from global Xb.
// ---------------------------------------------------------------------------
__global__ __launch_bounds__(256, 3)
void kjji_w(const ushort_t* __restrict__ Xb,
            const ushort_t* __restrict__ Wji, const ushort_t* __restrict__ Wkj,
            const float* __restrict__ bji, const float* __restrict__ bkj,
            const float* __restrict__ rbf, const float* __restrict__ Wr6,
            float* __restrict__ D, ushort_t* __restrict__ Cb, int M)
{
    __shared__ float W6s[NRR * HD];
    __shared__ float bjiS[HD], bkjS[HD];
    const int tid = threadIdx.x, wave = tid >> 6, lane = tid & 63;
    const int llo = lane & 15, lhi = lane >> 4;
    for (int i = tid; i < NRR * HD; i += 256) W6s[i] = Wr6[i];
    if (tid < HD) { bjiS[tid] = bji[tid]; bkjS[tid] = bkj[tid]; }
    __syncthreads();
    const int row0 = (blockIdx.x * 4 + wave) * 16;
    if (row0 >= M) return;

    // A fragments (k-contiguous 16B from global)
    short8 af[4];
    #pragma unroll
    for (int kc = 0; kc < 4; ++kc)
        af[kc] = *(const short8*)(Xb + (size_t)(row0 + llo) * HD + kc * 32 + lhi * 8);

    // rbf rows for kj epilogue: 24 contiguous floats
    float rb[4][6];
    {
        const float* rp = rbf + (size_t)(row0 + lhi * 4) * NRR;
        #pragma unroll
        for (int q = 0; q < 4; ++q)
            #pragma unroll
            for (int r = 0; r < NRR; ++r) rb[q][r] = rp[q * NRR + r];
    }

    #pragma unroll
    for (int s = 0; s < 2; ++s) {
        const ushort_t* W = s ? Wkj : Wji;
        floatx4 acc[8];
        #pragma unroll
        for (int tn = 0; tn < 8; ++tn) { acc[tn][0]=0.f; acc[tn][1]=0.f; acc[tn][2]=0.f; acc[tn][3]=0.f; }
        #pragma unroll
        for (int kc = 0; kc < 4; ++kc) {
            short8 bq[8];
            #pragma unroll
            for (int tn = 0; tn < 8; ++tn)
                bq[tn] = *(const short8*)(W + (size_t)(tn * 16 + llo) * HD + kc * 32 + lhi * 8);
            #pragma unroll
            for (int tn = 0; tn < 8; ++tn)
                acc[tn] = __builtin_amdgcn_mfma_f32_16x16x32_bf16(af[kc], bq[tn], acc[tn], 0, 0, 0);
        }
        #pragma unroll
        for (int tn = 0; tn < 8; ++tn) {
            int col = tn * 16 + llo;
            #pragma unroll
            for (int q = 0; q < 4; ++q) {
                int grow = row0 + lhi * 4 + q;
                if (grow >= M) continue;
                if (s == 0) {
                    D[(size_t)grow * HD + col] = siluf(acc[tn][q] + bjiS[col]);
                } else {
                    float rpv = 0.f;
                    #pragma unroll
                    for (int r = 0; r < NRR; ++r) rpv += rb[q][r] * W6s[r * HD + col];
                    Cb[(size_t)grow * HD + col] = f2us(siluf(acc[tn][q] + bkjS[col]) * rpv);
                }
            }
        }
    }
}

// ---------------------------------------------------------------------------
// Triplet accumulate (unchanged): G[e-c0, j*128+h] = sum sp[t,j]*Cb[ekj[t],h]
// ---------------------------------------------------------------------------
__global__ __launch_bounds__(256)
void trip_accum_k(const ushort_t* __restrict__ sp, const ushort_t* __restrict__ Cb,
                  const int* __restrict__ toffs, const int* __restrict__ tsorted,
                  const int* __restrict__ idx_kj, ushort_t* __restrict__ G,
                  int c0, int c1)
{
    int e = c0 + blockIdx.x * 2 + (threadIdx.x >> 7);
    if (e >= c1) return;
    int h = threadIdx.x & 127;
    float acc[NBB];
    #pragma unroll
    for (int j = 0; j < NBB; ++j) acc[j] = 0.f;
    int k1 = toffs[e + 1];
    for (int k = toffs[e]; k < k1; ++k) {
        int t = tsorted[k];
        int ekj = idx_kj[t];
        float v = us2f(Cb[(size_t)ekj * HD + h]);
        ushort8v s8 = *(const ushort8v*)(sp + (size_t)t * NBB);
        #pragma unroll
        for (int j = 0; j < NBB; ++j) acc[j] += us2f(s8[j]) * v;
    }
    ushort_t* g = G + (size_t)(e - c0) * 1024 + h;
    #pragma unroll
    for (int j = 0; j < NBB; ++j) g[j * HD] = f2us(acc[j]);
}

// ---------------------------------------------------------------------------
// Wave-autonomous K=1024 GEMM: D[c0+row,:] += G[row,:] @ Wm.  No LDS.
// ---------------------------------------------------------------------------
__global__ __launch_bounds__(256, 3)
void mgemmK_w(const ushort_t* __restrict__ G, int Mrows,
              const ushort_t* __restrict__ Wm, float* __restrict__ D, int c0)
{
    const int tid = threadIdx.x, wave = tid >> 6, lane = tid & 63;
    const int llo = lane & 15, lhi = lane >> 4;
    const int row0 = (blockIdx.x * 4 + wave) * 16;
    if (row0 >= Mrows) return;
    int arow = row0 + llo; if (arow >= Mrows) arow = Mrows - 1;

    floatx4 acc[8];
    #pragma unroll
    for (int tn = 0; tn < 8; ++tn) { acc[tn][0]=0.f; acc[tn][1]=0.f; acc[tn][2]=0.f; acc[tn][3]=0.f; }

    for (int kc = 0; kc < 32; ++kc) {
        short8 a8 = *(const short8*)(G + (size_t)arow * 1024 + kc * 32 + lhi * 8);
        short8 bq[8];
        #pragma unroll
        for (int tn = 0; tn < 8; ++tn)
            bq[tn] = *(const short8*)(Wm + (size_t)(tn * 16 + llo) * 1024 + kc * 32 + lhi * 8);
        #pragma unroll
        for (int tn = 0; tn < 8; ++tn)
            acc[tn] = __builtin_amdgcn_mfma_f32_16x16x32_bf16(a8, bq[tn], acc[tn], 0, 0, 0);
    }
    #pragma unroll
    for (int tn = 0; tn < 8; ++tn) {
        int col = tn * 16 + llo;
        #pragma unroll
        for (int q = 0; q < 4; ++q) {
            int grow = row0 + lhi * 4 + q;
            if (grow >= Mrows) continue;
            D[(size_t)(c0 + grow) * HD + col] += acc[tn][q];
        }
    }
}

// ---------------------------------------------------------------------------
// Wave-autonomous mega chain: 7 steps, trunk in registers, X written once.
// ---------------------------------------------------------------------------
__global__ __launch_bounds__(256, 3)
void mega_w(const float* __restrict__ Din, float* __restrict__ X, ushort_t* __restrict__ Xb,
            const ushort_t* __restrict__ Wc, const float* __restrict__ Bc, int M)
{
    __shared__ float bs[7 * HD];
    __shared__ ushort_t T[4][16][136];
    const int tid = threadIdx.x, wave = tid >> 6, lane = tid & 63;
    const int llo = lane & 15, lhi = lane >> 4;
    for (int i = tid; i < 7 * HD; i += 256) bs[i] = Bc[i];
    __syncthreads();
    const int row0 = (blockIdx.x * 4 + wave) * 16;
    if (row0 >= M) return;
    ushort_t (*Tw)[136] = T[wave];

    float hc[8][4];     // current activation tile, C-layout
    float trunk[8][4];  // residual trunk (valid from s=2)
    #pragma unroll
    for (int tn = 0; tn < 8; ++tn)
        #pragma unroll
        for (int q = 0; q < 4; ++q)
            hc[tn][q] = Din[(size_t)(row0 + lhi * 4 + q) * HD + tn * 16 + llo];

    #pragma unroll
    for (int s = 0; s < 7; ++s) {
        // repack hc -> wave-private LDS (bf16, A-layout source)
        #pragma unroll
        for (int tn = 0; tn < 8; ++tn)
            #pragma unroll
            for (int q = 0; q < 4; ++q)
                Tw[lhi * 4 + q][tn * 16 + llo] = f2us(hc[tn][q]);
        wave_lds_fence();

        const ushort_t* W = Wc + (size_t)s * MSZ;
        floatx4 acc[8];
        #pragma unroll
        for (int tn = 0; tn < 8; ++tn) { acc[tn][0]=0.f; acc[tn][1]=0.f; acc[tn][2]=0.f; acc[tn][3]=0.f; }
        #pragma unroll
        for (int kc = 0; kc < 4; ++kc) {
            short8 a8 = *(const short8*)&Tw[llo][kc * 32 + lhi * 8];
            short8 bq[8];
            #pragma unroll
            for (int tn = 0; tn < 8; ++tn)
                bq[tn] = *(const short8*)(W + (size_t)(tn * 16 + llo) * HD + kc * 32 + lhi * 8);
            #pragma unroll
            for (int tn = 0; tn < 8; ++tn)
                acc[tn] = __builtin_amdgcn_mfma_f32_16x16x32_bf16(a8, bq[tn], acc[tn], 0, 0, 0);
        }
        wave_lds_fence();   // all af reads done before next step's repack

        #pragma unroll
        for (int tn = 0; tn < 8; ++tn) {
            int col = tn * 16 + llo;
            #pragma unroll
            for (int q = 0; q < 4; ++q) {
                int grow = row0 + lhi * 4 + q;
                size_t gofs = (size_t)grow * HD + col;
                float t = siluf(acc[tn][q] + bs[s * HD + col]);
                if (s == 0)      hc[tn][q] = t;
                else if (s == 1) hc[tn][q] = t + Din[gofs];          // L2-hot re-read
                else if (s == 2) { hc[tn][q] = t + X[gofs]; trunk[tn][q] = hc[tn][q]; }
                else if (s == 3 || s == 5) hc[tn][q] = t;
                else { hc[tn][q] = t + trunk[tn][q]; trunk[tn][q] = hc[tn][q]; }
            }
        }
    }
    // final write: X fp32 + Xb bf16 (once)
    #pragma unroll
    for (int tn = 0; tn < 8; ++tn) {
        int col = tn * 16 + llo;
        #pragma unroll
        for (int q = 0; q < 4; ++q) {
            int grow = row0 + lhi * 4 + q;
            if (grow >= M) continue;
            size_t o = (size_t)grow * HD + col;
            X[o] = hc[tn][q];
            Xb[o] = f2us(hc[tn][q]);
        }
    }
}

// ---------------------------------------------------------------------------
// Wave-autonomous out-block: CSR atom gather (wave-private LDS) + 3 lins + dot
// ---------------------------------------------------------------------------
__global__ __launch_bounds__(256, 3)
void atomout_w(const ushort_t* __restrict__ Xb, const float* __restrict__ rbf,
               const float* __restrict__ Wr6, const int* __restrict__ eoffs,
               const int* __restrict__ esorted, const ushort_t* __restrict__ Wl,
               const float* __restrict__ bl, const float* __restrict__ wout,
               float* __restrict__ P, int M)
{
    __shared__ float W6s[NRR * HD];
    __shared__ float blS[3 * HD];
    __shared__ float woS[HD];
    __shared__ ushort_t T[4][16][136];
    const int tid = threadIdx.x, wave = tid >> 6, lane = tid & 63;
    const int llo = lane & 15, lhi = lane >> 4;
    for (int i = tid; i < NRR * HD; i += 256) W6s[i] = Wr6[i];
    for (int i = tid; i < 3 * HD; i += 256) blS[i] = bl[i];
    if (tid < HD) woS[tid] = wout[tid];
    __syncthreads();
    const int row0 = (blockIdx.x * 4 + wave) * 16;
    if (row0 >= M) return;
    ushort_t (*Tw)[136] = T[wave];

    // gather phase: 16 atoms, lanes = 64 cols x 2 halves
    for (int a_l = 0; a_l < 16; ++a_l) {
        int a = row0 + a_l;
        float acc0 = 0.f, acc1 = 0.f;
        int k1 = eoffs[a + 1];
        for (int k = eoffs[a]; k < k1; ++k) {
            int e = esorted[k];
            float r6[NRR];
            #pragma unroll
            for (int r = 0; r < NRR; ++r) r6[r] = rbf[(size_t)e * NRR + r];
            float rp0 = 0.f, rp1 = 0.f;
            #pragma unroll
            for (int r = 0; r < NRR; ++r) {
                rp0 += r6[r] * W6s[r * HD + lane];
                rp1 += r6[r] * W6s[r * HD + 64 + lane];
            }
            acc0 += rp0 * us2f(Xb[(size_t)e * HD + lane]);
            acc1 += rp1 * us2f(Xb[(size_t)e * HD + 64 + lane]);
        }
        Tw[a_l][lane] = f2us(acc0);
        Tw[a_l][64 + lane] = f2us(acc1);
    }
    wave_lds_fence();

    #pragma unroll
    for (int s = 0; s < 3; ++s) {
        const ushort_t* W = Wl + (size_t)s * MSZ;
        floatx4 acc[8];
        #pragma unroll
        for (int tn = 0; tn < 8; ++tn) { acc[tn][0]=0.f; acc[tn][1]=0.f; acc[tn][2]=0.f; acc[tn][3]=0.f; }
        #pragma unroll
        for (int kc = 0; kc < 4; ++kc) {
            short8 a8 = *(const short8*)&Tw[llo][kc * 32 + lhi * 8];
            short8 bq[8];
            #pragma unroll
            for (int tn = 0; tn < 8; ++tn)
                bq[tn] = *(const short8*)(W + (size_t)(tn * 16 + llo) * HD + kc * 32 + lhi * 8);
            #pragma unroll
            for (int tn = 0; tn < 8; ++tn)
                acc[tn] = __builtin_amdgcn_mfma_f32_16x16x32_bf16(a8, bq[tn], acc[tn], 0, 0, 0);
        }
        wave_lds_fence();

        if (s < 2) {
            #pragma unroll
            for (int tn = 0; tn < 8; ++tn) {
                int col = tn * 16 + llo;
                #pragma unroll
                for (int q = 0; q < 4; ++q)
                    Tw[lhi * 4 + q][col] = f2us(siluf(acc[tn][q] + blS[s * HD + col]));
            }
            wave_lds_fence();
        } else {
            #pragma unroll
            for (int q = 0; q < 4; ++q) {
                float v = 0.f;
                #pragma unroll
                for (int tn = 0; tn < 8; ++tn) {
                    int col = tn * 16 + llo;
                    v += siluf(acc[tn][q] + blS[2 * HD + col]) * woS[col];
                }
                v += __shfl_xor(v, 1); v += __shfl_xor(v, 2);
                v += __shfl_xor(v, 4); v += __shfl_xor(v, 8);
                int a = row0 + lhi * 4 + q;
                if (llo == 0 && a < M) P[a] += v;   // wave owns atom: plain RMW
            }
        }
    }
}

// ---------------- small kernels ----------------
__global__ void emb_lin_k(const float* __restrict__ emb_table, const float* __restrict__ emb_w,
                          float* __restrict__ A0, float* __restrict__ A1)
{
    __shared__ float er[HD];
    int a = blockIdx.x, h = threadIdx.x;
    er[h] = emb_table[a * HD + h];
    __syncthreads();
    float acc0 = 0.f, acc1 = 0.f;
    #pragma unroll 8
    for (int l = 0; l < HD; ++l) {
        float e = er[l];
        acc0 += e * emb_w[l * HD + h];
        acc1 += e * emb_w[(HD + l) * HD + h];
    }
    A0[a * HD + h] = acc0;
    A1[a * HD + h] = acc1;
}

__global__ void sbf_proj_k(const float* __restrict__ sbf, const float* __restrict__ W,
                           ushort_t* __restrict__ sp)
{
    __shared__ float Ws[NSNR * NBB];
    for (int s = threadIdx.x; s < NSNR * NBB; s += 256) Ws[s] = W[s];
    __syncthreads();
    int t = blockIdx.x * 256 + threadIdx.x;
    if (t >= NTRIP) return;
    float acc[NBB];
    #pragma unroll
    for (int n = 0; n < NBB; ++n) acc[n] = 0.f;
    #pragma unroll
    for (int r = 0; r < NSNR; ++r) {
        float v = sbf[(size_t)t * NSNR + r];
        #pragma unroll
        for (int n = 0; n < NBB; ++n) acc[n] += v * Ws[r * NBB + n];
    }
    #pragma unroll
    for (int n = 0; n < NBB; ++n) sp[(size_t)t * NBB + n] = f2us(acc[n]);
}

__global__ void graph_sum_k(const float* __restrict__ P, const int* __restrict__ batch,
                            float* __restrict__ outg)
{
    int a = blockIdx.x * 256 + threadIdx.x;
    if (a >= NATOMS) return;
    atomicAdd(&outg[batch[a]], P[a]);
}

// ---------------------------------------------------------------------------
extern "C" void kernel_launch(void* const* d_in, const int* in_sizes, int n_in,
                              void* d_out, int out_size, void* d_ws, size_t ws_size,
                              hipStream_t stream)
{
    const int*   z         = (const int*)  d_in[0];
    const float* rbf       = (const float*)d_in[1];
    const float* sbf       = (const float*)d_in[2];
    const int*   ii        = (const int*)  d_in[3];
    const int*   jj        = (const int*)  d_in[4];
    const int*   idx_kj    = (const int*)  d_in[5];
    const int*   idx_ji    = (const int*)  d_in[6];
    const int*   batch     = (const int*)  d_in[7];
    const float* emb_table = (const float*)d_in[8];
    const float* emb_rbf_w = (const float*)d_in[9];
    const float* emb_rbf_b = (const float*)d_in[10];
    const float* emb_w     = (const float*)d_in[11];
    const float* emb_b     = (const float*)d_in[12];
    const float* int_rbf_w = (const float*)d_in[13];
    const float* int_sbf_w = (const float*)d_in[14];
    const float* int_kj_w  = (const float*)d_in[15];
    const float* int_kj_b  = (const float*)d_in[16];
    const float* int_ji_w  = (const float*)d_in[17];
    const float* int_ji_b  = (const float*)d_in[18];
    const float* int_W     = (const float*)d_in[19];
    const float* int_bef_w = (const float*)d_in[20];
    const float* int_bef_b = (const float*)d_in[21];
    const float* int_lin_w = (const float*)d_in[22];
    const float* int_lin_b = (const float*)d_in[23];
    const float* int_aft_w = (const float*)d_in[24];
    const float* int_aft_b = (const float*)d_in[25];
    const float* out_rbf_w = (const float*)d_in[26];
    const float* out_lins_w= (const float*)d_in[27];
    const float* out_lins_b= (const float*)d_in[28];
    const float* out_w     = (const float*)d_in[29];
    float* d_outf          = (float*)d_out;

    const size_t EH = (size_t)NEDGES * HD;
    const int OFF_EMB = 0, OFF_KJ = 1, OFF_JI = 7, OFF_CHAIN = 13, OFF_OUTL = 55;

    char* base = (char*)d_ws;
    auto take = [&](size_t bytes) { char* p = base; base += (bytes + 255) & ~(size_t)255; return p; };
    float* bufA    = (float*)take(EH * 4);                     // X fp32
    float* bufD    = (float*)take(EH * 4);                     // x_ji + m
    ushort_t* Xb   = (ushort_t*)take(EH * 2);                  // X bf16 shadow
    ushort_t* Cb   = (ushort_t*)take(EH * 2);                  // x_kj bf16
    ushort_t* sbfp = (ushort_t*)take((size_t)NTRIP * NBB * 2); // sp bf16
    float* P_atom  = (float*)take((size_t)NATOMS * 4);
    float* A0      = (float*)take(95 * HD * 4);
    float* A1      = (float*)take(95 * HD * 4);
    float* bc      = (float*)take((size_t)NBLKS * 7 * HD * 4);
    int*   counts  = (int*)  take((size_t)(NEDGES + 1) * 4);
    int*   bsum    = (int*)  take(1024 * 4);
    int*   toffs   = (int*)  take((size_t)(NEDGES + 1) * 4);
    int*   eoffs   = (int*)  take((size_t)(NATOMS + 1) * 4);
    int*   tsorted = (int*)  take((size_t)NTRIP * 4);
    int*   esorted = (int*)  take((size_t)NEDGES * 4);
    ushort_t* w128 = (ushort_t*)take((size_t)76 * MSZ * 2);
    ushort_t* wM   = (ushort_t*)take((size_t)NBLKS * HD * 1024 * 2);
    size_t fixed   = (size_t)(base - (char*)d_ws);
    ushort_t* G    = (ushort_t*)base;

    int nch = 8;
    for (int c = 1; c <= 8; ++c) {
        size_t gb = (size_t)((NEDGES + c - 1) / c) * 1024 * 2;
        if (fixed + gb <= ws_size) { nch = c; break; }
    }
    const int CH = (NEDGES + nch - 1) / nch;

    auto zero = [&](float* p, size_t n) {
        zerof_k<<<((int)n + 255) / 256, 256, 0, stream>>>(p, (int)n);
    };

    // ---------------- weight prep ----------------
    transp128_k<<< 1, 256, 0, stream>>>(emb_w + 2 * MSZ, w128 + (size_t)OFF_EMB * MSZ);
    transp128_k<<< 6, 256, 0, stream>>>(int_kj_w,   w128 + (size_t)OFF_KJ  * MSZ);
    transp128_k<<< 6, 256, 0, stream>>>(int_ji_w,   w128 + (size_t)OFF_JI  * MSZ);
    for (int b = 0; b < NBLKS; ++b) {
        transp128_k<<<2, 256, 0, stream>>>(int_bef_w + (size_t)b * 2 * MSZ,
                                           w128 + (size_t)(OFF_CHAIN + b * 7) * MSZ);
        transp128_k<<<1, 256, 0, stream>>>(int_lin_w + (size_t)b * MSZ,
                                           w128 + (size_t)(OFF_CHAIN + b * 7 + 2) * MSZ);
        transp128_k<<<4, 256, 0, stream>>>(int_aft_w + (size_t)b * 4 * MSZ,
                                           w128 + (size_t)(OFF_CHAIN + b * 7 + 3) * MSZ);
    }
    transp128_k<<<21, 256, 0, stream>>>(out_lins_w, w128 + (size_t)OFF_OUTL * MSZ);
    castWM_k<<<(NBLKS * HD * 1024 + 255) / 256, 256, 0, stream>>>(int_W, wM, NBLKS * HD * 1024);
    pack_bc_k<<<NBLKS, 256, 0, stream>>>(int_bef_b, int_lin_b, int_aft_b, bc);

    // ---------------- CSR builds ----------------
    {
        zeroi_k<<<(NEDGES + 255) / 256, 256, 0, stream>>>(counts, NEDGES);
        hist_k<<<(NTRIP + 255) / 256, 256, 0, stream>>>(idx_ji, NTRIP, counts);
        int nb = (NEDGES + 255) / 256;
        blksum_k<<<nb, 256, 0, stream>>>(counts, NEDGES, bsum);
        scanb_k<<<1, 1024, 0, stream>>>(bsum, nb);
        scanfin_k<<<nb, 256, 0, stream>>>(counts, NEDGES, bsum, toffs);
        zeroi_k<<<(NEDGES + 255) / 256, 256, 0, stream>>>(counts, NEDGES);
        fill_k<<<(NTRIP + 255) / 256, 256, 0, stream>>>(idx_ji, NTRIP, toffs, counts, tsorted);
    }
    {
        zeroi_k<<<(NATOMS + 255) / 256, 256, 0, stream>>>(counts, NATOMS);
        hist_k<<<(NEDGES + 255) / 256, 256, 0, stream>>>(ii, NEDGES, counts);
        int nb = (NATOMS + 255) / 256;
        blksum_k<<<nb, 256, 0, stream>>>(counts, NATOMS, bsum);
        scanb_k<<<1, 1024, 0, stream>>>(bsum, nb);
        scanfin_k<<<nb, 256, 0, stream>>>(counts, NATOMS, bsum, eoffs);
        zeroi_k<<<(NATOMS + 255) / 256, 256, 0, stream>>>(counts, NATOMS);
        fill_k<<<(NEDGES + 255) / 256, 256, 0, stream>>>(ii, NEDGES, eoffs, counts, esorted);
    }

    const int EGRID  = (NEDGES + 127) / 128;           // emb_chain (block-tiled)
    const int EW     = (NEDGES / 16 + 3) / 4;          // wave-tiled E kernels
    const int AW     = (NATOMS / 16 + 3) / 4;          // wave-tiled atom kernel
    auto out_block = [&](int k) {
        atomout_w<<<AW, 256, 0, stream>>>(
            Xb, rbf, out_rbf_w + (size_t)k * NRR * HD, eoffs, esorted,
            w128 + (size_t)(OFF_OUTL + 3 * k) * MSZ,
            out_lins_b + (size_t)k * 3 * HD, out_w + (size_t)k * HD, P_atom, NATOMS);
    };

    // ---------------- Embedding ----------------
    emb_lin_k<<<95, HD, 0, stream>>>(emb_table, emb_w, A0, A1);
    emb_chain_k<<<EGRID, 256, 0, stream>>>(
        rbf, emb_rbf_w, emb_rbf_b, w128 + (size_t)OFF_EMB * MSZ,
        A0, A1, emb_b, z, ii, jj, bufA, Xb, NEDGES);

    zero(P_atom, NATOMS);
    out_block(0);

    // ---------------- Interaction blocks ----------------
    for (int b = 0; b < NBLKS; ++b) {
        sbf_proj_k<<<(NTRIP + 255) / 256, 256, 0, stream>>>(
            sbf, int_sbf_w + (size_t)b * NSNR * NBB, sbfp);

        kjji_w<<<EW, 256, 0, stream>>>(
            Xb, w128 + (size_t)(OFF_JI + b) * MSZ, w128 + (size_t)(OFF_KJ + b) * MSZ,
            int_ji_b + (size_t)b * HD, int_kj_b + (size_t)b * HD,
            rbf, int_rbf_w + (size_t)b * NRR * HD,
            bufD, Cb, NEDGES);

        for (int c = 0; c < nch; ++c) {
            int c0 = c * CH;
            int c1 = (c0 + CH < NEDGES) ? c0 + CH : NEDGES;
            if (c0 >= c1) break;
            int ne = c1 - c0;
            trip_accum_k<<<(ne + 1) / 2, 256, 0, stream>>>(
                sbfp, Cb, toffs, tsorted, idx_kj, G, c0, c1);
            int tw = ((ne + 15) / 16 + 3) / 4;
            mgemmK_w<<<tw, 256, 0, stream>>>(
                G, ne, wM + (size_t)b * HD * 1024, bufD, c0);
        }

        mega_w<<<EW, 256, 0, stream>>>(
            bufD, bufA, Xb, w128 + (size_t)(OFF_CHAIN + b * 7) * MSZ,
            bc + (size_t)b * 7 * HD, NEDGES);

        out_block(b + 1);
    }

    // ---------------- Final graph reduction ----------------
    zero(d_outf, NGRAPH);
    graph_sum_k<<<(NATOMS + 255) / 256, 256, 0, stream>>>(P_atom, batch, d_outf);
}